// Round 9
// baseline (152.509 us; speedup 1.0000x reference)
//
#include <hip/hip_runtime.h>

#define EMB 64

typedef float f32x4 __attribute__((ext_vector_type(4)));

// ---------- Kernel A: segment boundaries (segment_ids sorted) ----------
__global__ void seg_bounds_kernel(const int* __restrict__ seg,
                                  int* __restrict__ row_start,
                                  int T, int B) {
    int t = blockIdx.x * blockDim.x + threadIdx.x;
    if (t >= T) return;
    int s  = seg[t];
    int sp = (t == 0) ? -1 : seg[t - 1];
    for (int b = sp + 1; b <= s; ++b) row_start[b] = t;
    if (t == T - 1) {
        for (int b = s + 1; b <= B; ++b) row_start[b] = T;
    }
}

// ---------- Kernel Q: f32 -> int4 (per-row symmetric scale) ----------
__global__ __launch_bounds__(256) void cvt_q4_kernel(
    const float* __restrict__ src, uint* __restrict__ dst,
    float* __restrict__ scales, int nrows) {
    const int wave = (int)((blockIdx.x * blockDim.x + threadIdx.x) >> 6);
    const int lane = threadIdx.x & 63;
    const int g = lane >> 3, sub = lane & 7;
    const int r = wave * 8 + g;
    if (r >= nrows) return;

    const float* p = src + (size_t)r * EMB + (sub << 3);
    float e[8];
    #pragma unroll
    for (int k = 0; k < 8; ++k) e[k] = p[k];
    float mx = 0.f;
    #pragma unroll
    for (int k = 0; k < 8; ++k) mx = fmaxf(mx, fabsf(e[k]));
    mx = fmaxf(mx, __shfl_xor(mx, 1, 64));
    mx = fmaxf(mx, __shfl_xor(mx, 2, 64));
    mx = fmaxf(mx, __shfl_xor(mx, 4, 64));

    const float scale = mx * (1.0f / 7.5f);
    const float inv   = (mx > 0.f) ? (7.5f / mx) : 0.f;

    uint w = 0;
    #pragma unroll
    for (int k = 0; k < 8; ++k) {
        int q = (int)rintf(fmaf(e[k], inv, 7.5f));
        q = q < 0 ? 0 : (q > 15 ? 15 : q);
        w |= ((uint)q) << (4 * k);
    }
    dst[(size_t)r * 8 + sub] = w;
    if (sub == 0) scales[r] = scale;
}

// ---------- Kernel B v6: 8 rows/wave, 2 entries per VMEM, 4 chains ----------
// Group = 8 lanes. sub4=lane&3 covers dims [16*sub4,16*sub4+15] (uint2 = 16
// nibbles); pair=(lane>>2)&1 selects entry e / e+1. One q4 load = 2 entries
// per group; unroll x2 = 4 entries in flight.
__device__ __forceinline__ float qdot8(uint u, const float4 a, const float4 b) {
    const uint lo = u & 0x0F0F0F0Fu;
    const uint hi = (u >> 4) & 0x0F0F0F0Fu;
    const float e0 = (float)(lo & 0xffu),         e1 = (float)(hi & 0xffu);
    const float e2 = (float)((lo >> 8) & 0xffu),  e3 = (float)((hi >> 8) & 0xffu);
    const float e4 = (float)((lo >> 16) & 0xffu), e5 = (float)((hi >> 16) & 0xffu);
    const float e6 = (float)(lo >> 24),           e7 = (float)(hi >> 24);
    return e0*a.x + e1*a.y + e2*a.z + e3*a.w
         + e4*b.x + e5*b.y + e6*b.z + e7*b.w;
}

__global__ __launch_bounds__(256) void svdpp_main_q4(
    const int*   __restrict__ scientist_ids,
    const int*   __restrict__ paper_ids,
    const int*   __restrict__ flat_papers,
    const int*   __restrict__ row_start,
    const float* __restrict__ scientist_factors,
    const float* __restrict__ paper_factors,
    const uint*  __restrict__ imp_q4,
    const float* __restrict__ imp_scale,
    const float* __restrict__ scientist_bias,
    const float* __restrict__ paper_bias,
    float*       __restrict__ out,
    int B) {
    const int wave = (int)((blockIdx.x * blockDim.x + threadIdx.x) >> 6);
    const int lane = threadIdx.x & 63;
    const int g    = lane >> 3;          // group -> row
    const int sub  = lane & 7;
    const int sub4 = lane & 3;           // 16-dim slice
    const int pair = (lane >> 2) & 1;    // entry selector within a step
    const int b    = wave * 8 + g;
    if (b >= B) return;

    const int sid   = __builtin_nontemporal_load(scientist_ids + b);
    const int pid   = __builtin_nontemporal_load(paper_ids + b);
    const int start = __builtin_nontemporal_load(row_start + b);
    const int end   = __builtin_nontemporal_load(row_start + b + 1);

    // paper row (hot table): 4 cached float4 loads -> dims [16*sub4 .. +15]
    const float4* pf = reinterpret_cast<const float4*>(
        paper_factors + ((size_t)pid << 6)) + 4 * sub4;
    const float4 pe0 = pf[0], pe1 = pf[1], pe2 = pf[2], pe3 = pf[3];
    const float pesum = pe0.x+pe0.y+pe0.z+pe0.w + pe1.x+pe1.y+pe1.z+pe1.w
                      + pe2.x+pe2.y+pe2.z+pe2.w + pe3.x+pe3.y+pe3.z+pe3.w;

    // scientist row (zero-reuse): pair-0 lanes load 16 dims via 4 nt f32x4
    float base = 0.0f;
    if (pair == 0) {
        const f32x4* sf = reinterpret_cast<const f32x4*>(
            scientist_factors + ((size_t)sid << 6) + (sub4 << 4));
        const f32x4 s0 = __builtin_nontemporal_load(sf + 0);
        const f32x4 s1 = __builtin_nontemporal_load(sf + 1);
        const f32x4 s2 = __builtin_nontemporal_load(sf + 2);
        const f32x4 s3 = __builtin_nontemporal_load(sf + 3);
        base = s0.x*pe0.x + s0.y*pe0.y + s0.z*pe0.z + s0.w*pe0.w
             + s1.x*pe1.x + s1.y*pe1.y + s1.z*pe1.z + s1.w*pe1.w
             + s2.x*pe2.x + s2.y*pe2.y + s2.z*pe2.z + s2.w*pe2.w
             + s3.x*pe3.x + s3.y*pe3.y + s3.z*pe3.z + s3.w*pe3.w;
    }

    const float sb = __builtin_nontemporal_load(scientist_bias + sid);
    const float pb = __builtin_nontemporal_load(paper_bias + pid);

    // gather loop: 4 entries per iteration (2 per VMEM x unroll 2)
    float A0 = 0.f, A1 = 0.f, S0 = 0.f, S1 = 0.f;
    int e = start;
    for (; e + 4 <= end; e += 4) {
        const int pA = __builtin_nontemporal_load(flat_papers + e + pair);
        const int pB = __builtin_nontemporal_load(flat_papers + e + 2 + pair);
        const uint2 uA = reinterpret_cast<const uint2*>(imp_q4 + ((size_t)pA << 3))[sub4];
        const uint2 uB = reinterpret_cast<const uint2*>(imp_q4 + ((size_t)pB << 3))[sub4];
        const float sA = imp_scale[pA];
        const float sB = imp_scale[pB];
        A0 = fmaf(sA, qdot8(uA.x, pe0, pe1) + qdot8(uA.y, pe2, pe3), A0);  S0 += sA;
        A1 = fmaf(sB, qdot8(uB.x, pe0, pe1) + qdot8(uB.y, pe2, pe3), A1);  S1 += sB;
    }
    for (; e < end; e += 2) {
        const int idx = e + pair;
        if (idx < end) {
            const int p = __builtin_nontemporal_load(flat_papers + idx);
            const uint2 u = reinterpret_cast<const uint2*>(imp_q4 + ((size_t)p << 3))[sub4];
            const float s = imp_scale[p];
            A0 = fmaf(s, qdot8(u.x, pe0, pe1) + qdot8(u.y, pe2, pe3), A0);  S0 += s;
        }
    }
    // per-lane: A - 7.5*S*pesum_lane (pesum covers this lane's 16 dims)
    const float acc = (A0 + A1) - 7.5f * (S0 + S1) * pesum;

    const int n = end - start;
    const float scale = (n > 0) ? rsqrtf((float)n) : 0.0f;
    float v = base + scale * acc;

    // reduce within the 8-lane group (lane bits 0..2: sub4 + pair)
    v += __shfl_xor(v, 1, 64);
    v += __shfl_xor(v, 2, 64);
    v += __shfl_xor(v, 4, 64);

    if (sub == 0) {
        __builtin_nontemporal_store(v + sb + pb + 3.82f, out + b);
    }
}

// ---------- f32 fallback (ws too small) ----------
__global__ __launch_bounds__(256) void svdpp_main_f32(
    const int*   __restrict__ scientist_ids,
    const int*   __restrict__ paper_ids,
    const int*   __restrict__ flat_papers,
    const int*   __restrict__ row_start,
    const float* __restrict__ scientist_factors,
    const float* __restrict__ paper_factors,
    const float* __restrict__ implicit_factors,
    const float* __restrict__ scientist_bias,
    const float* __restrict__ paper_bias,
    float*       __restrict__ out,
    int B) {
    const int wave = (int)((blockIdx.x * blockDim.x + threadIdx.x) >> 6);
    const int lane = threadIdx.x & 63;
    if (wave >= B) return;
    const int b   = wave;
    const int g   = lane >> 4;
    const int sub = lane & 15;

    const int start = row_start[b];
    const int end   = row_start[b + 1];
    const int n     = end - start;

    float4 accA = make_float4(0.f,0.f,0.f,0.f);
    int i = start;
    for (; i < end; i += 4) {
        const int e = i + g;
        if (e < end) {
            const int p = flat_papers[e];
            const float4 r = *reinterpret_cast<const float4*>(
                implicit_factors + ((size_t)p << 6) + (sub << 2));
            accA.x += r.x; accA.y += r.y; accA.z += r.z; accA.w += r.w;
        }
    }

    const float scale = (n > 0) ? rsqrtf((float)n) : 0.0f;
    const int sid = scientist_ids[b];
    const int pid = paper_ids[b];
    const float4 se = *reinterpret_cast<const float4*>(
        scientist_factors + ((size_t)sid << 6) + (sub << 2));
    const float4 pe = *reinterpret_cast<const float4*>(
        paper_factors + ((size_t)pid << 6) + (sub << 2));

    const float basedot = se.x*pe.x + se.y*pe.y + se.z*pe.z + se.w*pe.w;
    const float tdot    = accA.x*pe.x + accA.y*pe.y + accA.z*pe.z + accA.w*pe.w;
    float v = scale * tdot + ((g == 0) ? basedot : 0.0f);

    #pragma unroll
    for (int off = 1; off < 64; off <<= 1) v += __shfl_xor(v, off, 64);

    if (lane == 0) {
        out[b] = v + scientist_bias[sid] + paper_bias[pid] + 3.82f;
    }
}

extern "C" void kernel_launch(void* const* d_in, const int* in_sizes, int n_in,
                              void* d_out, int out_size, void* d_ws, size_t ws_size,
                              hipStream_t stream) {
    const int* scientist_ids       = (const int*)d_in[0];
    const int* paper_ids           = (const int*)d_in[1];
    const int* flat_papers         = (const int*)d_in[2];
    const int* segment_ids         = (const int*)d_in[3];
    const float* scientist_factors = (const float*)d_in[4];
    const float* paper_factors     = (const float*)d_in[5];
    const float* implicit_factors  = (const float*)d_in[6];
    const float* scientist_bias    = (const float*)d_in[7];
    const float* paper_bias        = (const float*)d_in[8];
    float* out = (float*)d_out;

    const int B      = in_sizes[0];
    const int T      = in_sizes[2];
    const int IMP_N  = in_sizes[6];          // NUM_PAPERS * EMB
    const int NROWS  = IMP_N / EMB;          // NUM_PAPERS

    int* row_start = (int*)d_ws;                              // (B+1) ints
    size_t off_tab = (((size_t)(B + 1) * 4) + 63) & ~(size_t)63;
    uint*  imp_q4    = (uint*)((char*)d_ws + off_tab);        // NROWS * 32B
    float* imp_scale = (float*)((char*)d_ws + off_tab + (size_t)NROWS * 32);
    const size_t need = off_tab + (size_t)NROWS * 32 + (size_t)NROWS * 4;

    {
        const int threads = 256;
        const int blocks  = (T + threads - 1) / threads;
        seg_bounds_kernel<<<blocks, threads, 0, stream>>>(segment_ids, row_start, T, B);
    }

    if (ws_size >= need) {
        {
            const int threads = 256;                  // 32 rows per block
            const int blocks  = (NROWS + 31) / 32;
            cvt_q4_kernel<<<blocks, threads, 0, stream>>>(
                implicit_factors, imp_q4, imp_scale, NROWS);
        }
        const int threads = 256;                      // 32 output rows per block
        const int blocks  = (B + 31) / 32;
        svdpp_main_q4<<<blocks, threads, 0, stream>>>(
            scientist_ids, paper_ids, flat_papers, row_start,
            scientist_factors, paper_factors, imp_q4, imp_scale,
            scientist_bias, paper_bias, out, B);
    } else {
        const int threads = 256;
        const int blocks  = (B + 3) / 4;
        svdpp_main_f32<<<blocks, threads, 0, stream>>>(
            scientist_ids, paper_ids, flat_papers, row_start,
            scientist_factors, paper_factors, implicit_factors,
            scientist_bias, paper_bias, out, B);
    }
}

// Round 10
// 120.392 us; speedup vs baseline: 1.2668x; 1.2668x over previous
//
#include <hip/hip_runtime.h>

#define EMB 64

// ---------- Kernel A: segment boundaries (segment_ids sorted) ----------
__global__ void seg_bounds_kernel(const int* __restrict__ seg,
                                  int* __restrict__ row_start,
                                  int T, int B) {
    int t = blockIdx.x * blockDim.x + threadIdx.x;
    if (t >= T) return;
    int s  = seg[t];
    int sp = (t == 0) ? -1 : seg[t - 1];
    for (int b = sp + 1; b <= s; ++b) row_start[b] = t;
    if (t == T - 1) {
        for (int b = s + 1; b <= B; ++b) row_start[b] = T;
    }
}

// ---------- Kernel Q: f32 -> int4 (per-row symmetric scale) ----------
__global__ __launch_bounds__(256) void cvt_q4_kernel(
    const float* __restrict__ src, uint* __restrict__ dst,
    float* __restrict__ scales, int nrows) {
    const int wave = (int)((blockIdx.x * blockDim.x + threadIdx.x) >> 6);
    const int lane = threadIdx.x & 63;
    const int g = lane >> 3, sub = lane & 7;
    const int r = wave * 8 + g;
    if (r >= nrows) return;

    const float* p = src + (size_t)r * EMB + (sub << 3);
    float e[8];
    #pragma unroll
    for (int k = 0; k < 8; ++k) e[k] = p[k];
    float mx = 0.f;
    #pragma unroll
    for (int k = 0; k < 8; ++k) mx = fmaxf(mx, fabsf(e[k]));
    mx = fmaxf(mx, __shfl_xor(mx, 1, 64));
    mx = fmaxf(mx, __shfl_xor(mx, 2, 64));
    mx = fmaxf(mx, __shfl_xor(mx, 4, 64));

    const float scale = mx * (1.0f / 7.5f);
    const float inv   = (mx > 0.f) ? (7.5f / mx) : 0.f;

    uint w = 0;
    #pragma unroll
    for (int k = 0; k < 8; ++k) {
        int q = (int)rintf(fmaf(e[k], inv, 7.5f));
        q = q < 0 ? 0 : (q > 15 ? 15 : q);
        w |= ((uint)q) << (4 * k);
    }
    dst[(size_t)r * 8 + sub] = w;
    if (sub == 0) scales[r] = scale;
}

// ---------- Kernel B v7: R8 structure + 4 dependent chains in flight ----
// Wave = 8 groups x 8 lanes; group g owns row wave*8+g; lane sub=lane&7
// covers dims [8*sub..8*sub+7] (uint = 8 nibbles). Per q4 VMEM inst the
// wave touches 8 distinct 32B rows (one per group) — keep it that way.
__device__ __forceinline__ float qdot8(uint u, const float4 a, const float4 b) {
    const uint lo = u & 0x0F0F0F0Fu;
    const uint hi = (u >> 4) & 0x0F0F0F0Fu;
    const float e0 = (float)(lo & 0xffu),         e1 = (float)(hi & 0xffu);
    const float e2 = (float)((lo >> 8) & 0xffu),  e3 = (float)((hi >> 8) & 0xffu);
    const float e4 = (float)((lo >> 16) & 0xffu), e5 = (float)((hi >> 16) & 0xffu);
    const float e6 = (float)(lo >> 24),           e7 = (float)(hi >> 24);
    return e0*a.x + e1*a.y + e2*a.z + e3*a.w
         + e4*b.x + e5*b.y + e6*b.z + e7*b.w;
}

__global__ __launch_bounds__(256) void svdpp_main_q4(
    const int*   __restrict__ scientist_ids,
    const int*   __restrict__ paper_ids,
    const int*   __restrict__ flat_papers,
    const int*   __restrict__ row_start,
    const float* __restrict__ scientist_factors,
    const float* __restrict__ paper_factors,
    const uint*  __restrict__ imp_q4,
    const float* __restrict__ imp_scale,
    const float* __restrict__ scientist_bias,
    const float* __restrict__ paper_bias,
    float*       __restrict__ out,
    int B) {
    const int wave = (int)((blockIdx.x * blockDim.x + threadIdx.x) >> 6);
    const int lane = threadIdx.x & 63;
    const int g    = lane >> 3;        // group -> row
    const int sub  = lane & 7;         // dims [8*sub, 8*sub+7]
    const int b    = wave * 8 + g;
    if (b >= B) return;

    const int sid   = __builtin_nontemporal_load(scientist_ids + b);
    const int pid   = __builtin_nontemporal_load(paper_ids + b);
    const int start = row_start[b];
    const int end   = row_start[b + 1];

    // paper row (hot 25.6MB table): plain cached float4 loads
    const float4* pf = reinterpret_cast<const float4*>(
        paper_factors + ((size_t)pid << 6)) + 2 * sub;
    const float4 pe0 = pf[0];
    const float4 pe1 = pf[1];
    const float pesum = pe0.x + pe0.y + pe0.z + pe0.w
                      + pe1.x + pe1.y + pe1.z + pe1.w;

    // scientist row (zero-reuse 256MB table): scalar nt loads
    const float* sf = scientist_factors + ((size_t)sid << 6) + (sub << 3);
    float se[8];
    #pragma unroll
    for (int k = 0; k < 8; ++k) se[k] = __builtin_nontemporal_load(sf + k);

    const float sb = __builtin_nontemporal_load(scientist_bias + sid);
    const float pb = __builtin_nontemporal_load(paper_bias + pid);

    const float base = se[0]*pe0.x + se[1]*pe0.y + se[2]*pe0.z + se[3]*pe0.w
                     + se[4]*pe1.x + se[5]*pe1.y + se[6]*pe1.z + se[7]*pe1.w;

    // gather loop: 4 independent chains; ids issued first, then gathers.
    float A0 = 0.f, A1 = 0.f, A2 = 0.f, A3 = 0.f;
    float S0 = 0.f, S1 = 0.f, S2 = 0.f, S3 = 0.f;
    int e = start;
    for (; e + 4 <= end; e += 4) {
        const int p0 = flat_papers[e];
        const int p1 = flat_papers[e + 1];
        const int p2 = flat_papers[e + 2];
        const int p3 = flat_papers[e + 3];
        const uint u0 = imp_q4[((size_t)p0 << 3) + sub];
        const uint u1 = imp_q4[((size_t)p1 << 3) + sub];
        const uint u2 = imp_q4[((size_t)p2 << 3) + sub];
        const uint u3 = imp_q4[((size_t)p3 << 3) + sub];
        const float s0 = imp_scale[p0];
        const float s1 = imp_scale[p1];
        const float s2 = imp_scale[p2];
        const float s3 = imp_scale[p3];
        A0 = fmaf(s0, qdot8(u0, pe0, pe1), A0);  S0 += s0;
        A1 = fmaf(s1, qdot8(u1, pe0, pe1), A1);  S1 += s1;
        A2 = fmaf(s2, qdot8(u2, pe0, pe1), A2);  S2 += s2;
        A3 = fmaf(s3, qdot8(u3, pe0, pe1), A3);  S3 += s3;
    }
    for (; e < end; ++e) {
        const int p = flat_papers[e];
        const uint u = imp_q4[((size_t)p << 3) + sub];
        const float s = imp_scale[p];
        A0 = fmaf(s, qdot8(u, pe0, pe1), A0);  S0 += s;
    }
    const float acc = ((A0 + A1) + (A2 + A3))
                    - 7.5f * ((S0 + S1) + (S2 + S3)) * pesum;

    const int n = end - start;
    const float scale = (n > 0) ? rsqrtf((float)n) : 0.0f;
    float v = base + scale * acc;

    // reduce within the 8-lane group (lane bits 0..2)
    v += __shfl_xor(v, 1, 64);
    v += __shfl_xor(v, 2, 64);
    v += __shfl_xor(v, 4, 64);

    if (sub == 0) {
        __builtin_nontemporal_store(v + sb + pb + 3.82f, out + b);
    }
}

// ---------- f32 fallback (ws too small) ----------
__global__ __launch_bounds__(256) void svdpp_main_f32(
    const int*   __restrict__ scientist_ids,
    const int*   __restrict__ paper_ids,
    const int*   __restrict__ flat_papers,
    const int*   __restrict__ row_start,
    const float* __restrict__ scientist_factors,
    const float* __restrict__ paper_factors,
    const float* __restrict__ implicit_factors,
    const float* __restrict__ scientist_bias,
    const float* __restrict__ paper_bias,
    float*       __restrict__ out,
    int B) {
    const int wave = (int)((blockIdx.x * blockDim.x + threadIdx.x) >> 6);
    const int lane = threadIdx.x & 63;
    if (wave >= B) return;
    const int b   = wave;
    const int g   = lane >> 4;
    const int sub = lane & 15;

    const int start = row_start[b];
    const int end   = row_start[b + 1];
    const int n     = end - start;

    float4 accA = make_float4(0.f,0.f,0.f,0.f);
    int i = start;
    for (; i < end; i += 4) {
        const int e = i + g;
        if (e < end) {
            const int p = flat_papers[e];
            const float4 r = *reinterpret_cast<const float4*>(
                implicit_factors + ((size_t)p << 6) + (sub << 2));
            accA.x += r.x; accA.y += r.y; accA.z += r.z; accA.w += r.w;
        }
    }

    const float scale = (n > 0) ? rsqrtf((float)n) : 0.0f;
    const int sid = scientist_ids[b];
    const int pid = paper_ids[b];
    const float4 se = *reinterpret_cast<const float4*>(
        scientist_factors + ((size_t)sid << 6) + (sub << 2));
    const float4 pe = *reinterpret_cast<const float4*>(
        paper_factors + ((size_t)pid << 6) + (sub << 2));

    const float basedot = se.x*pe.x + se.y*pe.y + se.z*pe.z + se.w*pe.w;
    const float tdot    = accA.x*pe.x + accA.y*pe.y + accA.z*pe.z + accA.w*pe.w;
    float v = scale * tdot + ((g == 0) ? basedot : 0.0f);

    #pragma unroll
    for (int off = 1; off < 64; off <<= 1) v += __shfl_xor(v, off, 64);

    if (lane == 0) {
        out[b] = v + scientist_bias[sid] + paper_bias[pid] + 3.82f;
    }
}

extern "C" void kernel_launch(void* const* d_in, const int* in_sizes, int n_in,
                              void* d_out, int out_size, void* d_ws, size_t ws_size,
                              hipStream_t stream) {
    const int* scientist_ids       = (const int*)d_in[0];
    const int* paper_ids           = (const int*)d_in[1];
    const int* flat_papers         = (const int*)d_in[2];
    const int* segment_ids         = (const int*)d_in[3];
    const float* scientist_factors = (const float*)d_in[4];
    const float* paper_factors     = (const float*)d_in[5];
    const float* implicit_factors  = (const float*)d_in[6];
    const float* scientist_bias    = (const float*)d_in[7];
    const float* paper_bias        = (const float*)d_in[8];
    float* out = (float*)d_out;

    const int B      = in_sizes[0];
    const int T      = in_sizes[2];
    const int IMP_N  = in_sizes[6];          // NUM_PAPERS * EMB
    const int NROWS  = IMP_N / EMB;          // NUM_PAPERS

    int* row_start = (int*)d_ws;                              // (B+1) ints
    size_t off_tab = (((size_t)(B + 1) * 4) + 63) & ~(size_t)63;
    uint*  imp_q4    = (uint*)((char*)d_ws + off_tab);        // NROWS * 32B
    float* imp_scale = (float*)((char*)d_ws + off_tab + (size_t)NROWS * 32);
    const size_t need = off_tab + (size_t)NROWS * 32 + (size_t)NROWS * 4;

    {
        const int threads = 256;
        const int blocks  = (T + threads - 1) / threads;
        seg_bounds_kernel<<<blocks, threads, 0, stream>>>(segment_ids, row_start, T, B);
    }

    if (ws_size >= need) {
        {
            const int threads = 256;                  // 32 rows per block
            const int blocks  = (NROWS + 31) / 32;
            cvt_q4_kernel<<<blocks, threads, 0, stream>>>(
                implicit_factors, imp_q4, imp_scale, NROWS);
        }
        const int threads = 256;                      // 32 output rows per block
        const int blocks  = (B + 31) / 32;
        svdpp_main_q4<<<blocks, threads, 0, stream>>>(
            scientist_ids, paper_ids, flat_papers, row_start,
            scientist_factors, paper_factors, imp_q4, imp_scale,
            scientist_bias, paper_bias, out, B);
    } else {
        const int threads = 256;
        const int blocks  = (B + 3) / 4;
        svdpp_main_f32<<<blocks, threads, 0, stream>>>(
            scientist_ids, paper_ids, flat_papers, row_start,
            scientist_factors, paper_factors, implicit_factors,
            scientist_bias, paper_bias, out, B);
    }
}